// Round 8
// baseline (215.462 us; speedup 1.0000x reference)
//
#include <hip/hip_runtime.h>
#include <stdint.h>

#define NORI   197
#define FRAMES 8
#define NTOK   1576
#define BATCH  8
#define NHEAD  12
#define CDIM   768
#define MG     204
#define TOKENS 12608

typedef _Float16 half8 __attribute__((ext_vector_type(8)));
typedef float floatx4 __attribute__((ext_vector_type(4)));

typedef const __attribute__((address_space(1))) void GPTR;
typedef __attribute__((address_space(3))) void LPTR;

__device__ __forceinline__ int gather_idx(int m) {
    if (m < 8) return m * NORI;
    int u = m - 8;
    int f, t;
    if (u < 100) { f = u / 25; t = u - f * 25; }
    else         { f = 4 + (u - 100) / 24; t = (u - 100) - (f - 4) * 24; }
    return f * NORI + 1 + f + 8 * t;
}
__device__ __forceinline__ int col_frame(int m) {  // m in [8,204)
    int u = m - 8;
    return (u < 100) ? (u / 25) : (4 + (u - 100) / 24);
}

// Bijective XCD-chunked remap (m204 form): block bid runs on XCD bid%8; give XCD k
// the k-th contiguous chunk of work ids so producer/consumer chunks coincide.
__device__ __forceinline__ int xcd_chunk(int bid, int nwg) {
    int xcd = bid & 7, j = bid >> 3;
    int q = nwg >> 3, r = nwg & 7;
    int base = (xcd < r) ? xcd * (q + 1) : r * (q + 1) + (xcd - r) * q;
    return base + j;
}

// ---------------- fused fp32 -> fp16 cast of x, qkv_w, proj_w ----------------
// R7-proven: x-region blocks XCD-chunk remapped so batch b's xh is written on the
// XCD whose gemm_qkv blocks read it. Weight blocks unmapped (read by all).
__global__ __launch_bounds__(256) void cast_all(
    const float* __restrict__ x, const float* __restrict__ qkvw,
    const float* __restrict__ projw, _Float16* __restrict__ out)
{
    const int n1 = TOKENS * CDIM / 8, n2 = 3 * CDIM * CDIM / 8, n3 = CDIM * CDIM / 8;
    const int nxb = n1 / 256;                       // 4728, divisible by 8
    int bx = blockIdx.x;
    int i;
    if (bx < nxb) i = xcd_chunk(bx, nxb) * 256 + threadIdx.x;
    else          i = bx * 256 + threadIdx.x;
    if (i >= n1 + n2 + n3) return;
    const float* src; int off;
    if (i < n1)           { src = x;     off = i; }
    else if (i < n1 + n2) { src = qkvw;  off = i - n1; }
    else                  { src = projw; off = i - n1 - n2; }
    float4 a = ((const float4*)src)[2 * off];
    float4 b = ((const float4*)src)[2 * off + 1];
    half8 o = { (_Float16)a.x, (_Float16)a.y, (_Float16)a.z, (_Float16)a.w,
                (_Float16)b.x, (_Float16)b.y, (_Float16)b.z, (_Float16)b.w };
    ((half8*)out)[i] = o;
}

// ------------- MFMA GEMM body: A via LDS (R0-proven loop), B via reg prefetch ------
// R8 hybrid: the 2-barrier-per-K-step tax (m233; R4/R5 showed insensitivity to
// occupancy & prefetch depth) is paid per barrier-coupled load. B is L2-hot weights
// and its direct per-lane fragment address is BIT-EXACT vs the staged path (swizzles
// cancel; empirically proven by R6's exact absmax). So: keep A on gload_lds+barrier
// (unchanged, proven R0/R7), move B to registers prefetched ONE ITERATION AHEAD into
// named even/odd arrays (static indexing, rule #20). Per iter only 2 loads remain
// barrier-coupled; the 4 B-loads get a full iteration of L2-latency hiding.
// vmcnt(6) before barrier: outstanding = A(it+1)x2 + B(it+1)x4; A(it) is older than
// the already-consumed B(it) so it is provably drained. MFMA order and operand
// values identical -> output bit-identical (absmax must stay 4.882812e-4).
// LDS = 2 x 128x32 halfs = 16 KB.
template <int OUT_F32>
__device__ __forceinline__ void gemm_body(
    const _Float16* __restrict__ A, const _Float16* __restrict__ W,
    const float* __restrict__ bias, void* __restrict__ Y,
    int M, int Woff, int ldY, int gather, int r0, int c0,
    _Float16* As0, _Float16* As1)
{
    const int tid = threadIdx.x;
    const int w = tid >> 6, l = tid & 63;
    const int wm = (w >> 1) * 64, wn = (w & 1) * 64;
    const int lm = l & 15, lq = l >> 4;

    // A staging (unchanged from R0/R7): wave w stages rows [w*32, w*32+32)
    const _Float16* sa[2];
    int soff[2];
#pragma unroll
    for (int i = 0; i < 2; i++) {
        int rt = w * 32 + i * 16 + (l >> 2);
        int cg = (l & 3) ^ ((l >> 3) & 3);       // swizzled global chunk
        int ra = min(r0 + rt, M - 1);
        if (gather) { int b = ra / MG; int m = ra - b * MG; ra = b * NTOK + gather_idx(m); }
        sa[i] = A + (size_t)ra * CDIM + cg * 8;
        soff[i] = (w * 32 + i * 16) * 32;
    }

    // B direct fragment pointers (R6-proven addressing: chunk = lq)
    const _Float16* pb[4];
#pragma unroll
    for (int t = 0; t < 4; t++) {
        int col = c0 + wn + t * 16 + lm;
        pb[t] = W + (size_t)(Woff + col) * CDIM + lq * 8;
    }

    // prologue: stage A(0) into buf0; load B(0) into b0
#pragma unroll
    for (int i = 0; i < 2; i++)
        __builtin_amdgcn_global_load_lds((GPTR*)sa[i], (LPTR*)(As0 + soff[i]), 16, 0, 0);
    half8 b0[4], b1[4];
#pragma unroll
    for (int t = 0; t < 4; t++) b0[t] = *(const half8*)(pb[t]);

    floatx4 acc[4][4] = {};
    const int fc = ((l >> 4) ^ ((l >> 1) & 3)) * 8;
    const int mrow = lm;

#pragma unroll
    for (int it = 0; it < 24; it++) {
        const _Float16* Ac = (it & 1) ? As1 : As0;
        _Float16* An = (it & 1) ? As0 : As1;

        if (it < 23) {
            int kb = (it + 1) * 32;
#pragma unroll
            for (int i = 0; i < 2; i++)
                __builtin_amdgcn_global_load_lds((GPTR*)(sa[i] + kb), (LPTR*)(An + soff[i]), 16, 0, 0);
            if (it & 1) {
#pragma unroll
                for (int t = 0; t < 4; t++) b0[t] = *(const half8*)(pb[t] + kb);
            } else {
#pragma unroll
                for (int t = 0; t < 4; t++) b1[t] = *(const half8*)(pb[t] + kb);
            }
            __builtin_amdgcn_s_waitcnt(0x0076);   // vmcnt(6) lgkm(0): A(it) LDS done
        } else {
            __builtin_amdgcn_s_waitcnt(0x0074);   // vmcnt(4): A(23) done, B(23) may fly
        }
        __builtin_amdgcn_s_barrier();             // A buf 'cur' collectively staged
        __builtin_amdgcn_sched_barrier(0);        // no ds_read hoisting above barrier

        half8 af[4];
#pragma unroll
        for (int t = 0; t < 4; t++)
            af[t] = *(const half8*)&Ac[(wm + t * 16 + mrow) * 32 + fc];
        if (it & 1) {
#pragma unroll
            for (int mt = 0; mt < 4; mt++)
#pragma unroll
                for (int nt = 0; nt < 4; nt++)
                    acc[mt][nt] = __builtin_amdgcn_mfma_f32_16x16x32_f16(af[mt], b1[nt], acc[mt][nt], 0, 0, 0);
        } else {
#pragma unroll
            for (int mt = 0; mt < 4; mt++)
#pragma unroll
                for (int nt = 0; nt < 4; nt++)
                    acc[mt][nt] = __builtin_amdgcn_mfma_f32_16x16x32_f16(af[mt], b0[nt], acc[mt][nt], 0, 0, 0);
        }

        __builtin_amdgcn_sched_barrier(0);        // no ds_read sinking below release
        __builtin_amdgcn_s_barrier();             // release A buf for overwrite
    }

#pragma unroll
    for (int nt = 0; nt < 4; nt++) {
        int col = c0 + wn + nt * 16 + lm;
        float bv = bias ? bias[col] : 0.f;
#pragma unroll
        for (int mt = 0; mt < 4; mt++) {
#pragma unroll
            for (int r = 0; r < 4; r++) {
                int row = r0 + wm + mt * 16 + lq * 4 + r;
                if (row < M) {
                    if (OUT_F32) ((float*)Y)[(size_t)row * ldY + col] = acc[mt][nt][r] + bv;
                    else ((_Float16*)Y)[(size_t)row * ldY + col] = (_Float16)acc[mt][nt][r];
                }
            }
        }
    }
}

// Q GEMM: 594 work ids (grid padded to 600 to keep the KV part's XCD phase);
// xcd_chunk puts batch b's token rows on XCD b. KV GEMM: 156 ids, same alignment.
__global__ __launch_bounds__(256) void gemm_qkv(
    const _Float16* __restrict__ xh, const _Float16* __restrict__ qkvwh,
    _Float16* __restrict__ Qh, _Float16* __restrict__ KVh)
{
    __shared__ __align__(16) _Float16 As0[128 * 32];
    __shared__ __align__(16) _Float16 As1[128 * 32];
    int bx = blockIdx.x;
    if (bx < 600) {
        if (bx >= 594) return;                    // 6 pad blocks
        int wg = xcd_chunk(bx, 594);
        int rb = wg / 6, cb = wg - rb * 6;
        gemm_body<0>(xh, qkvwh, nullptr, Qh, TOKENS, 0, CDIM, 0,
                     rb * 128, cb * 128, As0, As1);
    } else {
        int b2 = bx - 600;
        int wg = xcd_chunk(b2, 156);
        int rb = wg / 12, cb = wg - rb * 12;
        gemm_body<0>(xh, qkvwh, nullptr, KVh, BATCH * MG, CDIM, 1536, 1,
                     rb * 128, cb * 128, As0, As1);
    }
}

__global__ __launch_bounds__(256) void gemm_proj(
    const _Float16* __restrict__ AOh, const _Float16* __restrict__ projwh,
    const float* __restrict__ bias, float* __restrict__ out)
{
    __shared__ __align__(16) _Float16 As0[128 * 32];
    __shared__ __align__(16) _Float16 As1[128 * 32];
    int wg = xcd_chunk(blockIdx.x, 594);
    int rb = wg / 6, cb = wg - rb * 6;
    gemm_body<1>(AOh, projwh, bias, out, TOKENS, 0, CDIM, 0,
                 rb * 128, cb * 128, As0, As1);
}

// ---------------- fused masked attention, MFMA (R7 exact) ----------------
// 1-D grid 480, batch b on XCD b (b = id%8): Q/KV reads and AO write stay in the
// XCD-local L2. block = (b,h) x 320 q-rows. K/V staged ONCE. 80384 B LDS -> 2/CU.
__global__ __launch_bounds__(256, 2) void attn_mfma(
    const _Float16* __restrict__ Qh, const _Float16* __restrict__ KVh,
    _Float16* __restrict__ AOh)
{
    __shared__ __align__(16) _Float16 Ks[204 * 64];  // [row][chunk^(row&7)]
    __shared__ __align__(16) _Float16 Vt[64 * 208];
    __shared__ __align__(16) _Float16 Ps[64 * 216];  // wave w owns rows [w*16, +16)

    const int tid = threadIdx.x;
    const int id = blockIdx.x;
    const int b = id & 7;                 // XCD = id%8 -> batch b on XCD b
    const int j = id >> 3;                // [0,60)
    const int h = j % NHEAD;
    const int qc0 = (j / NHEAD) * 320;

    for (int e = tid; e < MG * 8; e += 256) {
        int row = e >> 3, c8 = e & 7;
        half8 v = *(const half8*)&KVh[(size_t)(b * MG + row) * 1536 + h * 64 + c8 * 8];
        *(half8*)&Ks[row * 64 + ((c8 ^ (row & 7)) * 8)] = v;
    }
    {
        const int d0 = (tid >> 5) * 8, lmp = tid & 31;
#pragma unroll
        for (int mo = 0; mo < 7; mo++) {
            int mp = mo * 32 + lmp;
            if (mp >= 208) continue;
            half8 v = {};
            if (mp < MG) v = *(const half8*)&KVh[(size_t)(b * MG + mp) * 1536 + 768 + h * 64 + d0];
#pragma unroll
            for (int jj = 0; jj < 8; jj++) Vt[(d0 + jj) * 208 + mp] = v[jj];
        }
    }
    __syncthreads();

    const int w = tid >> 6, l = tid & 63;
    const int lm = l & 15, lq = l >> 4;

    int cf[13];
#pragma unroll
    for (int t = 0; t < 13; t++) {
        int col = t * 16 + lm;
        cf[t] = (col < 8) ? -1 : (col >= MG ? -2 : col_frame(col));
    }

    _Float16* Pw = &Ps[(w * 16) * 216];

    for (int t5 = 0; t5 < 5; t5++) {
        const int rb = qc0 + t5 * 64 + w * 16;
        if (rb >= NTOK) break;   // per-wave exit; no barriers below

        floatx4 acc[13] = {};
        const int qrowA = min(rb + lm, NTOK - 1);
        const _Float16* qbase = Qh + (size_t)(b * NTOK + qrowA) * CDIM + h * 64;
        __builtin_amdgcn_s_setprio(1);
#pragma unroll
        for (int ks = 0; ks < 64; ks += 32) {
            half8 aq = *(const half8*)(qbase + ks + lq * 8);
#pragma unroll
            for (int t = 0; t < 13; t++) {
                half8 bk = *(const half8*)&Ks[(t * 16 + lm) * 64 + (((ks >> 3) + lq) ^ (lm & 7)) * 8];
                acc[t] = __builtin_amdgcn_mfma_f32_16x16x32_f16(aq, bk, acc[t], 0, 0, 0);
            }
        }
        __builtin_amdgcn_s_setprio(0);

#pragma unroll
        for (int r = 0; r < 4; r++) {
            int qrow = min(rb + lq * 4 + r, NTOK - 1);
            int rf = qrow / NORI;
            float sv[13];
            float mx = -1e30f;
#pragma unroll
            for (int t = 0; t < 13; t++) {
                float s = acc[t][r] * 0.125f;
                s *= (cf[t] == -1 || cf[t] == rf) ? 1.f : 0.8f;
                if (cf[t] == -2) s = -1e30f;
                sv[t] = s;
                mx = fmaxf(mx, s);
            }
#pragma unroll
            for (int off = 1; off < 16; off <<= 1) mx = fmaxf(mx, __shfl_xor(mx, off, 64));
            float sum = 0.f;
#pragma unroll
            for (int t = 0; t < 13; t++) { sv[t] = __expf(sv[t] - mx); sum += sv[t]; }
#pragma unroll
            for (int off = 1; off < 16; off <<= 1) sum += __shfl_xor(sum, off, 64);
            float inv = 1.f / sum;
#pragma unroll
            for (int t = 0; t < 13; t++) acc[t][r] = sv[t] * inv;
        }

#pragma unroll
        for (int t = 0; t < 13; t++)
#pragma unroll
            for (int r = 0; r < 4; r++)
                Pw[(lq * 4 + r) * 216 + t * 16 + lm] = (_Float16)acc[t][r];

        floatx4 oacc[4] = {};
        const _Float16* prow = &Pw[lm * 216];
        __builtin_amdgcn_s_setprio(1);
#pragma unroll
        for (int ks = 0; ks < 192; ks += 32) {
            half8 ap = *(const half8*)(prow + ks + lq * 8);
#pragma unroll
            for (int t = 0; t < 4; t++) {
                half8 bv = *(const half8*)&Vt[(t * 16 + lm) * 208 + ks + lq * 8];
                oacc[t] = __builtin_amdgcn_mfma_f32_16x16x32_f16(ap, bv, oacc[t], 0, 0, 0);
            }
        }
        {
            typedef _Float16 half4v __attribute__((ext_vector_type(4)));
            half4v ap4 = *(const half4v*)(prow + 192 + lq * 4);
#pragma unroll
            for (int t = 0; t < 4; t++) {
                half4v bv4 = *(const half4v*)&Vt[(t * 16 + lm) * 208 + 192 + lq * 4];
                oacc[t] = __builtin_amdgcn_mfma_f32_16x16x16f16(ap4, bv4, oacc[t], 0, 0, 0);
            }
        }
        __builtin_amdgcn_s_setprio(0);

#pragma unroll
        for (int t = 0; t < 4; t++)
#pragma unroll
            for (int r = 0; r < 4; r++) {
                int qrow = rb + lq * 4 + r;
                if (qrow < NTOK)
                    AOh[(size_t)(b * NTOK + qrow) * CDIM + h * 64 + t * 16 + lm] = (_Float16)oacc[t][r];
            }
    }
}

extern "C" void kernel_launch(void* const* d_in, const int* in_sizes, int n_in,
                              void* d_out, int out_size, void* d_ws, size_t ws_size,
                              hipStream_t stream) {
    const float* x      = (const float*)d_in[0];
    const float* qkv_w  = (const float*)d_in[1];
    const float* proj_w = (const float*)d_in[2];
    const float* proj_b = (const float*)d_in[3];
    float* out = (float*)d_out;

    _Float16* xh     = (_Float16*)d_ws;
    _Float16* qkvwh  = xh + (size_t)TOKENS * CDIM;
    _Float16* projwh = qkvwh + (size_t)3 * CDIM * CDIM;
    _Float16* Qh     = projwh + (size_t)CDIM * CDIM;
    _Float16* KVh    = Qh + (size_t)TOKENS * CDIM;
    _Float16* AOh    = KVh + (size_t)(BATCH * MG) * 1536;

    dim3 blk(256);
    const int ncast = (TOKENS * CDIM + 3 * CDIM * CDIM + CDIM * CDIM) / 8;
    cast_all<<<dim3((ncast + 255) / 256), blk, 0, stream>>>(x, qkv_w, proj_w, xh);

    gemm_qkv<<<dim3(600 + 156), blk, 0, stream>>>(xh, qkvwh, Qh, KVh);

    attn_mfma<<<dim3(480), blk, 0, stream>>>(Qh, KVh, AOh);

    gemm_proj<<<dim3(594), blk, 0, stream>>>(AOh, projwh, proj_b, out);
}

// Round 9
// 198.618 us; speedup vs baseline: 1.0848x; 1.0848x over previous
//
#include <hip/hip_runtime.h>
#include <stdint.h>

#define NORI   197
#define FRAMES 8
#define NTOK   1576
#define BATCH  8
#define NHEAD  12
#define CDIM   768
#define MG     204
#define TOKENS 12608

typedef _Float16 half8 __attribute__((ext_vector_type(8)));
typedef float floatx4 __attribute__((ext_vector_type(4)));

typedef const __attribute__((address_space(1))) void GPTR;
typedef __attribute__((address_space(3))) void LPTR;

__device__ __forceinline__ int gather_idx(int m) {
    if (m < 8) return m * NORI;
    int u = m - 8;
    int f, t;
    if (u < 100) { f = u / 25; t = u - f * 25; }
    else         { f = 4 + (u - 100) / 24; t = (u - 100) - (f - 4) * 24; }
    return f * NORI + 1 + f + 8 * t;
}
__device__ __forceinline__ int col_frame(int m) {  // m in [8,204)
    int u = m - 8;
    return (u < 100) ? (u / 25) : (4 + (u - 100) / 24);
}

// Bijective XCD-chunked remap (m204 form): block bid runs on XCD bid%8; give XCD k
// the k-th contiguous chunk of work ids so producer/consumer chunks coincide.
__device__ __forceinline__ int xcd_chunk(int bid, int nwg) {
    int xcd = bid & 7, j = bid >> 3;
    int q = nwg >> 3, r = nwg & 7;
    int base = (xcd < r) ? xcd * (q + 1) : r * (q + 1) + (xcd - r) * q;
    return base + j;
}

// ---------------- fused fp32 -> fp16 cast of x, qkv_w, proj_w ----------------
// R7-proven: x-region blocks XCD-chunk remapped so batch b's xh is written on the
// XCD whose gemm_qkv blocks read it. Weight blocks unmapped (read by all).
__global__ __launch_bounds__(256) void cast_all(
    const float* __restrict__ x, const float* __restrict__ qkvw,
    const float* __restrict__ projw, _Float16* __restrict__ out)
{
    const int n1 = TOKENS * CDIM / 8, n2 = 3 * CDIM * CDIM / 8, n3 = CDIM * CDIM / 8;
    const int nxb = n1 / 256;                       // 4728, divisible by 8
    int bx = blockIdx.x;
    int i;
    if (bx < nxb) i = xcd_chunk(bx, nxb) * 256 + threadIdx.x;
    else          i = bx * 256 + threadIdx.x;
    if (i >= n1 + n2 + n3) return;
    const float* src; int off;
    if (i < n1)           { src = x;     off = i; }
    else if (i < n1 + n2) { src = qkvw;  off = i - n1; }
    else                  { src = projw; off = i - n1 - n2; }
    float4 a = ((const float4*)src)[2 * off];
    float4 b = ((const float4*)src)[2 * off + 1];
    half8 o = { (_Float16)a.x, (_Float16)a.y, (_Float16)a.z, (_Float16)a.w,
                (_Float16)b.x, (_Float16)b.y, (_Float16)b.z, (_Float16)b.w };
    ((half8*)out)[i] = o;
}

// -------- MFMA GEMM body, 128x128, double-pumped K: 2 chunks per barrier-pair ------
// R9: the ~40us/GEMM floor survived occupancy x3 (R4), prefetch depth 2 (R5), and
// de-staging (R6/R8) -> the cost is the FIXED per-sync-period tax (m233: stage+
// vmcnt-drain+barrier+refill), paid once per BK=32 step (24x). This round halves the
// count: 4 A + 4 B chunk-buffers of the PROVEN [128][32] layout (64 KB LDS); each
// iter stages chunk-pair {2it+2,2it+3} (8 loads/wave), vmcnt(8), ONE barrier-pair,
// computes TWO chunks (32 MFMA) in the original chunk order. Per-chunk addressing,
// fragment math, and accumulation order are byte-identical to R7 -> bit-identical
// output (absmax must stay 4.882812e-4). Overwrite safety: pair P is restaged at
// iter it+1, one full barrier2 after its iter-it reads. sched_barrier pins retained.
#define CHSZ (128 * 32)

template <int OUT_F32>
__device__ __forceinline__ void gemm_body(
    const _Float16* __restrict__ A, const _Float16* __restrict__ W,
    const float* __restrict__ bias, void* __restrict__ Y,
    int M, int Woff, int ldY, int gather, int r0, int c0,
    _Float16* As, _Float16* Bs)
{
    const int tid = threadIdx.x;
    const int w = tid >> 6, l = tid & 63;
    const int wm = (w >> 1) * 64, wn = (w & 1) * 64;

    const _Float16* sa[2];
    const _Float16* sb[2];
    int soff[2];
#pragma unroll
    for (int i = 0; i < 2; i++) {
        int rt = w * 32 + i * 16 + (l >> 2);
        int cg = (l & 3) ^ ((l >> 3) & 3);       // swizzled global chunk
        int ra = min(r0 + rt, M - 1);
        if (gather) { int b = ra / MG; int m = ra - b * MG; ra = b * NTOK + gather_idx(m); }
        sa[i] = A + (size_t)ra * CDIM + cg * 8;
        sb[i] = W + (size_t)(Woff + c0 + rt) * CDIM + cg * 8;
        soff[i] = (w * 32 + i * 16) * 32;
    }

    // prologue: stage chunks 0,1 into pair0 (buffers 0,1)
#pragma unroll
    for (int c = 0; c < 2; c++)
#pragma unroll
        for (int i = 0; i < 2; i++) {
            __builtin_amdgcn_global_load_lds((GPTR*)(sa[i] + c * 32), (LPTR*)(As + c * CHSZ + soff[i]), 16, 0, 0);
            __builtin_amdgcn_global_load_lds((GPTR*)(sb[i] + c * 32), (LPTR*)(Bs + c * CHSZ + soff[i]), 16, 0, 0);
        }

    floatx4 acc[4][4] = {};
    const int fc = ((l >> 4) ^ ((l >> 1) & 3)) * 8;
    const int mrow = l & 15;

#pragma unroll
    for (int it = 0; it < 12; it++) {
        const _Float16* AcA = As + ((it & 1) ? 2 : 0) * CHSZ;   // chunk 2it
        const _Float16* AcB = AcA + CHSZ;                       // chunk 2it+1
        const _Float16* BcA = Bs + ((it & 1) ? 2 : 0) * CHSZ;
        const _Float16* BcB = BcA + CHSZ;
        _Float16* An = As + ((it & 1) ? 0 : 2) * CHSZ;
        _Float16* Bn = Bs + ((it & 1) ? 0 : 2) * CHSZ;

        if (it < 11) {
            int kb = (2 * it + 2) * 32;
#pragma unroll
            for (int c = 0; c < 2; c++)
#pragma unroll
                for (int i = 0; i < 2; i++) {
                    __builtin_amdgcn_global_load_lds((GPTR*)(sa[i] + kb + c * 32),
                                                     (LPTR*)(An + c * CHSZ + soff[i]), 16, 0, 0);
                    __builtin_amdgcn_global_load_lds((GPTR*)(sb[i] + kb + c * 32),
                                                     (LPTR*)(Bn + c * CHSZ + soff[i]), 16, 0, 0);
                }
            __builtin_amdgcn_s_waitcnt(0x0078);   // vmcnt(8) lgkm(0): current pair staged
        } else {
            __builtin_amdgcn_s_waitcnt(0x0070);   // vmcnt(0) lgkm(0)
        }
        __builtin_amdgcn_s_barrier();             // pair 'cur' collectively staged
        __builtin_amdgcn_sched_barrier(0);        // no ds_read hoisting above barrier

        half8 af[4], bf[4];
        // chunk 2it (identical addressing to the proven single-chunk body)
#pragma unroll
        for (int t = 0; t < 4; t++) {
            af[t] = *(const half8*)&AcA[(wm + t * 16 + mrow) * 32 + fc];
            bf[t] = *(const half8*)&BcA[(wn + t * 16 + mrow) * 32 + fc];
        }
#pragma unroll
        for (int mt = 0; mt < 4; mt++)
#pragma unroll
            for (int nt = 0; nt < 4; nt++)
                acc[mt][nt] = __builtin_amdgcn_mfma_f32_16x16x32_f16(af[mt], bf[nt], acc[mt][nt], 0, 0, 0);
        // chunk 2it+1
#pragma unroll
        for (int t = 0; t < 4; t++) {
            af[t] = *(const half8*)&AcB[(wm + t * 16 + mrow) * 32 + fc];
            bf[t] = *(const half8*)&BcB[(wn + t * 16 + mrow) * 32 + fc];
        }
#pragma unroll
        for (int mt = 0; mt < 4; mt++)
#pragma unroll
            for (int nt = 0; nt < 4; nt++)
                acc[mt][nt] = __builtin_amdgcn_mfma_f32_16x16x32_f16(af[mt], bf[nt], acc[mt][nt], 0, 0, 0);

        __builtin_amdgcn_sched_barrier(0);        // no ds_read sinking below release
        __builtin_amdgcn_s_barrier();             // release pair 'cur' for overwrite
    }

#pragma unroll
    for (int nt = 0; nt < 4; nt++) {
        int col = c0 + wn + nt * 16 + (l & 15);
        float bv = bias ? bias[col] : 0.f;
#pragma unroll
        for (int mt = 0; mt < 4; mt++) {
#pragma unroll
            for (int r = 0; r < 4; r++) {
                int row = r0 + wm + mt * 16 + (l >> 4) * 4 + r;
                if (row < M) {
                    if (OUT_F32) ((float*)Y)[(size_t)row * ldY + col] = acc[mt][nt][r] + bv;
                    else ((_Float16*)Y)[(size_t)row * ldY + col] = (_Float16)acc[mt][nt][r];
                }
            }
        }
    }
}

// Q GEMM: 594 work ids (grid padded to 600 to keep the KV part's XCD phase);
// xcd_chunk puts batch b's token rows on XCD b. KV GEMM: 156 ids, same alignment.
__global__ __launch_bounds__(256) void gemm_qkv(
    const _Float16* __restrict__ xh, const _Float16* __restrict__ qkvwh,
    _Float16* __restrict__ Qh, _Float16* __restrict__ KVh)
{
    __shared__ __align__(16) _Float16 As[4 * CHSZ];
    __shared__ __align__(16) _Float16 Bs[4 * CHSZ];
    int bx = blockIdx.x;
    if (bx < 600) {
        if (bx >= 594) return;                    // 6 pad blocks
        int wg = xcd_chunk(bx, 594);
        int rb = wg / 6, cb = wg - rb * 6;
        gemm_body<0>(xh, qkvwh, nullptr, Qh, TOKENS, 0, CDIM, 0,
                     rb * 128, cb * 128, As, Bs);
    } else {
        int b2 = bx - 600;
        int wg = xcd_chunk(b2, 156);
        int rb = wg / 12, cb = wg - rb * 12;
        gemm_body<0>(xh, qkvwh, nullptr, KVh, BATCH * MG, CDIM, 1536, 1,
                     rb * 128, cb * 128, As, Bs);
    }
}

__global__ __launch_bounds__(256) void gemm_proj(
    const _Float16* __restrict__ AOh, const _Float16* __restrict__ projwh,
    const float* __restrict__ bias, float* __restrict__ out)
{
    __shared__ __align__(16) _Float16 As[4 * CHSZ];
    __shared__ __align__(16) _Float16 Bs[4 * CHSZ];
    int wg = xcd_chunk(blockIdx.x, 594);
    int rb = wg / 6, cb = wg - rb * 6;
    gemm_body<1>(AOh, projwh, bias, out, TOKENS, 0, CDIM, 0,
                 rb * 128, cb * 128, As, Bs);
}

// ---------------- fused masked attention, MFMA (R7 exact) ----------------
// 1-D grid 480, batch b on XCD b (b = id%8): Q/KV reads and AO write stay in the
// XCD-local L2. block = (b,h) x 320 q-rows. K/V staged ONCE. 80384 B LDS -> 2/CU.
__global__ __launch_bounds__(256, 2) void attn_mfma(
    const _Float16* __restrict__ Qh, const _Float16* __restrict__ KVh,
    _Float16* __restrict__ AOh)
{
    __shared__ __align__(16) _Float16 Ks[204 * 64];  // [row][chunk^(row&7)]
    __shared__ __align__(16) _Float16 Vt[64 * 208];
    __shared__ __align__(16) _Float16 Ps[64 * 216];  // wave w owns rows [w*16, +16)

    const int tid = threadIdx.x;
    const int id = blockIdx.x;
    const int b = id & 7;                 // XCD = id%8 -> batch b on XCD b
    const int j = id >> 3;                // [0,60)
    const int h = j % NHEAD;
    const int qc0 = (j / NHEAD) * 320;

    for (int e = tid; e < MG * 8; e += 256) {
        int row = e >> 3, c8 = e & 7;
        half8 v = *(const half8*)&KVh[(size_t)(b * MG + row) * 1536 + h * 64 + c8 * 8];
        *(half8*)&Ks[row * 64 + ((c8 ^ (row & 7)) * 8)] = v;
    }
    {
        const int d0 = (tid >> 5) * 8, lmp = tid & 31;
#pragma unroll
        for (int mo = 0; mo < 7; mo++) {
            int mp = mo * 32 + lmp;
            if (mp >= 208) continue;
            half8 v = {};
            if (mp < MG) v = *(const half8*)&KVh[(size_t)(b * MG + mp) * 1536 + 768 + h * 64 + d0];
#pragma unroll
            for (int jj = 0; jj < 8; jj++) Vt[(d0 + jj) * 208 + mp] = v[jj];
        }
    }
    __syncthreads();

    const int w = tid >> 6, l = tid & 63;
    const int lm = l & 15, lq = l >> 4;

    int cf[13];
#pragma unroll
    for (int t = 0; t < 13; t++) {
        int col = t * 16 + lm;
        cf[t] = (col < 8) ? -1 : (col >= MG ? -2 : col_frame(col));
    }

    _Float16* Pw = &Ps[(w * 16) * 216];

    for (int t5 = 0; t5 < 5; t5++) {
        const int rb = qc0 + t5 * 64 + w * 16;
        if (rb >= NTOK) break;   // per-wave exit; no barriers below

        floatx4 acc[13] = {};
        const int qrowA = min(rb + lm, NTOK - 1);
        const _Float16* qbase = Qh + (size_t)(b * NTOK + qrowA) * CDIM + h * 64;
        __builtin_amdgcn_s_setprio(1);
#pragma unroll
        for (int ks = 0; ks < 64; ks += 32) {
            half8 aq = *(const half8*)(qbase + ks + lq * 8);
#pragma unroll
            for (int t = 0; t < 13; t++) {
                half8 bk = *(const half8*)&Ks[(t * 16 + lm) * 64 + (((ks >> 3) + lq) ^ (lm & 7)) * 8];
                acc[t] = __builtin_amdgcn_mfma_f32_16x16x32_f16(aq, bk, acc[t], 0, 0, 0);
            }
        }
        __builtin_amdgcn_s_setprio(0);

#pragma unroll
        for (int r = 0; r < 4; r++) {
            int qrow = min(rb + lq * 4 + r, NTOK - 1);
            int rf = qrow / NORI;
            float sv[13];
            float mx = -1e30f;
#pragma unroll
            for (int t = 0; t < 13; t++) {
                float s = acc[t][r] * 0.125f;
                s *= (cf[t] == -1 || cf[t] == rf) ? 1.f : 0.8f;
                if (cf[t] == -2) s = -1e30f;
                sv[t] = s;
                mx = fmaxf(mx, s);
            }
#pragma unroll
            for (int off = 1; off < 16; off <<= 1) mx = fmaxf(mx, __shfl_xor(mx, off, 64));
            float sum = 0.f;
#pragma unroll
            for (int t = 0; t < 13; t++) { sv[t] = __expf(sv[t] - mx); sum += sv[t]; }
#pragma unroll
            for (int off = 1; off < 16; off <<= 1) sum += __shfl_xor(sum, off, 64);
            float inv = 1.f / sum;
#pragma unroll
            for (int t = 0; t < 13; t++) acc[t][r] = sv[t] * inv;
        }

#pragma unroll
        for (int t = 0; t < 13; t++)
#pragma unroll
            for (int r = 0; r < 4; r++)
                Pw[(lq * 4 + r) * 216 + t * 16 + lm] = (_Float16)acc[t][r];

        floatx4 oacc[4] = {};
        const _Float16* prow = &Pw[lm * 216];
        __builtin_amdgcn_s_setprio(1);
#pragma unroll
        for (int ks = 0; ks < 192; ks += 32) {
            half8 ap = *(const half8*)(prow + ks + lq * 8);
#pragma unroll
            for (int t = 0; t < 4; t++) {
                half8 bv = *(const half8*)&Vt[(t * 16 + lm) * 208 + ks + lq * 8];
                oacc[t] = __builtin_amdgcn_mfma_f32_16x16x32_f16(ap, bv, oacc[t], 0, 0, 0);
            }
        }
        {
            typedef _Float16 half4v __attribute__((ext_vector_type(4)));
            half4v ap4 = *(const half4v*)(prow + 192 + lq * 4);
#pragma unroll
            for (int t = 0; t < 4; t++) {
                half4v bv4 = *(const half4v*)&Vt[(t * 16 + lm) * 208 + 192 + lq * 4];
                oacc[t] = __builtin_amdgcn_mfma_f32_16x16x16f16(ap4, bv4, oacc[t], 0, 0, 0);
            }
        }
        __builtin_amdgcn_s_setprio(0);

#pragma unroll
        for (int t = 0; t < 4; t++)
#pragma unroll
            for (int r = 0; r < 4; r++) {
                int qrow = rb + lq * 4 + r;
                if (qrow < NTOK)
                    AOh[(size_t)(b * NTOK + qrow) * CDIM + h * 64 + t * 16 + lm] = (_Float16)oacc[t][r];
            }
    }
}

extern "C" void kernel_launch(void* const* d_in, const int* in_sizes, int n_in,
                              void* d_out, int out_size, void* d_ws, size_t ws_size,
                              hipStream_t stream) {
    const float* x      = (const float*)d_in[0];
    const float* qkv_w  = (const float*)d_in[1];
    const float* proj_w = (const float*)d_in[2];
    const float* proj_b = (const float*)d_in[3];
    float* out = (float*)d_out;

    _Float16* xh     = (_Float16*)d_ws;
    _Float16* qkvwh  = xh + (size_t)TOKENS * CDIM;
    _Float16* projwh = qkvwh + (size_t)3 * CDIM * CDIM;
    _Float16* Qh     = projwh + (size_t)CDIM * CDIM;
    _Float16* KVh    = Qh + (size_t)TOKENS * CDIM;
    _Float16* AOh    = KVh + (size_t)(BATCH * MG) * 1536;

    dim3 blk(256);
    const int ncast = (TOKENS * CDIM + 3 * CDIM * CDIM + CDIM * CDIM) / 8;
    cast_all<<<dim3((ncast + 255) / 256), blk, 0, stream>>>(x, qkv_w, proj_w, xh);

    gemm_qkv<<<dim3(600 + 156), blk, 0, stream>>>(xh, qkvwh, Qh, KVh);

    attn_mfma<<<dim3(480), blk, 0, stream>>>(Qh, KVh, AOh);

    gemm_proj<<<dim3(594), blk, 0, stream>>>(AOh, projwh, proj_b, out);
}

// Round 10
// 185.954 us; speedup vs baseline: 1.1587x; 1.0681x over previous
//
#include <hip/hip_runtime.h>
#include <stdint.h>

#define NORI   197
#define FRAMES 8
#define NTOK   1576
#define BATCH  8
#define NHEAD  12
#define CDIM   768
#define MG     204
#define TOKENS 12608

typedef _Float16 half8 __attribute__((ext_vector_type(8)));
typedef float floatx4 __attribute__((ext_vector_type(4)));

typedef const __attribute__((address_space(1))) void GPTR;
typedef __attribute__((address_space(3))) void LPTR;

__device__ __forceinline__ int gather_idx(int m) {
    if (m < 8) return m * NORI;
    int u = m - 8;
    int f, t;
    if (u < 100) { f = u / 25; t = u - f * 25; }
    else         { f = 4 + (u - 100) / 24; t = (u - 100) - (f - 4) * 24; }
    return f * NORI + 1 + f + 8 * t;
}
__device__ __forceinline__ int col_frame(int m) {  // m in [8,204)
    int u = m - 8;
    return (u < 100) ? (u / 25) : (4 + (u - 100) / 24);
}

// Bijective XCD-chunked remap (m204 form): block bid runs on XCD bid%8; give XCD k
// the k-th contiguous chunk of work ids so producer/consumer chunks coincide.
__device__ __forceinline__ int xcd_chunk(int bid, int nwg) {
    int xcd = bid & 7, j = bid >> 3;
    int q = nwg >> 3, r = nwg & 7;
    int base = (xcd < r) ? xcd * (q + 1) : r * (q + 1) + (xcd - r) * q;
    return base + j;
}

// ---------------- fused fp32 -> fp16 cast of x, qkv_w, proj_w ----------------
// R7-proven: x-region blocks XCD-chunk remapped so batch b's xh is written on the
// XCD whose gemm_qkv blocks read it. Weight blocks unmapped (read by all).
__global__ __launch_bounds__(256) void cast_all(
    const float* __restrict__ x, const float* __restrict__ qkvw,
    const float* __restrict__ projw, _Float16* __restrict__ out)
{
    const int n1 = TOKENS * CDIM / 8, n2 = 3 * CDIM * CDIM / 8, n3 = CDIM * CDIM / 8;
    const int nxb = n1 / 256;                       // 4728, divisible by 8
    int bx = blockIdx.x;
    int i;
    if (bx < nxb) i = xcd_chunk(bx, nxb) * 256 + threadIdx.x;
    else          i = bx * 256 + threadIdx.x;
    if (i >= n1 + n2 + n3) return;
    const float* src; int off;
    if (i < n1)           { src = x;     off = i; }
    else if (i < n1 + n2) { src = qkvw;  off = i - n1; }
    else                  { src = projw; off = i - n1 - n2; }
    float4 a = ((const float4*)src)[2 * off];
    float4 b = ((const float4*)src)[2 * off + 1];
    half8 o = { (_Float16)a.x, (_Float16)a.y, (_Float16)a.z, (_Float16)a.w,
                (_Float16)b.x, (_Float16)b.y, (_Float16)b.z, (_Float16)b.w };
    ((half8*)out)[i] = o;
}

// ---------------- MFMA GEMM body, 128x128, BK=32, double-buffered (R0 exact) -------
// The 2-phase structure's per-MFLOP cost (~1350 cy/MFLOP) is invariant across tile
// shape (R4), residency (R4), prefetch depth (R5), staging style (R6/R8), and
// barrier count (R9). Keep the best-measured form; optimize FILL, not structure.
template <int OUT_F32>
__device__ __forceinline__ void gemm_body(
    const _Float16* __restrict__ A, const _Float16* __restrict__ W,
    const float* __restrict__ bias, void* __restrict__ Y,
    int M, int Woff, int ldY, int gather, int r0, int c0,
    _Float16* As0, _Float16* Bs0, _Float16* As1, _Float16* Bs1)
{
    const int tid = threadIdx.x;
    const int w = tid >> 6, l = tid & 63;
    const int wm = (w >> 1) * 64, wn = (w & 1) * 64;

    const _Float16* sa[2];
    const _Float16* sb[2];
    int soff[2];
#pragma unroll
    for (int i = 0; i < 2; i++) {
        int rt = w * 32 + i * 16 + (l >> 2);
        int cg = (l & 3) ^ ((l >> 3) & 3);       // swizzled global chunk
        int ra = min(r0 + rt, M - 1);
        if (gather) { int b = ra / MG; int m = ra - b * MG; ra = b * NTOK + gather_idx(m); }
        sa[i] = A + (size_t)ra * CDIM + cg * 8;
        sb[i] = W + (size_t)(Woff + c0 + rt) * CDIM + cg * 8;
        soff[i] = (w * 32 + i * 16) * 32;
    }

    // prologue: stage tile 0 into buf0
#pragma unroll
    for (int i = 0; i < 2; i++) {
        __builtin_amdgcn_global_load_lds((GPTR*)sa[i], (LPTR*)(As0 + soff[i]), 16, 0, 0);
        __builtin_amdgcn_global_load_lds((GPTR*)sb[i], (LPTR*)(Bs0 + soff[i]), 16, 0, 0);
    }

    floatx4 acc[4][4] = {};
    const int fc = ((l >> 4) ^ ((l >> 1) & 3)) * 8;
    const int mrow = l & 15;

#pragma unroll
    for (int it = 0; it < 24; it++) {
        const _Float16* Ac = (it & 1) ? As1 : As0;
        const _Float16* Bc = (it & 1) ? Bs1 : Bs0;
        _Float16* An = (it & 1) ? As0 : As1;
        _Float16* Bn = (it & 1) ? Bs0 : Bs1;

        if (it < 23) {
            int kb = (it + 1) * 32;
#pragma unroll
            for (int i = 0; i < 2; i++) {
                __builtin_amdgcn_global_load_lds((GPTR*)(sa[i] + kb), (LPTR*)(An + soff[i]), 16, 0, 0);
                __builtin_amdgcn_global_load_lds((GPTR*)(sb[i] + kb), (LPTR*)(Bn + soff[i]), 16, 0, 0);
            }
            __builtin_amdgcn_s_waitcnt(0x0074);   // vmcnt(4) lgkmcnt(0)
        } else {
            __builtin_amdgcn_s_waitcnt(0x0070);   // vmcnt(0) lgkmcnt(0)
        }
        __builtin_amdgcn_s_barrier();             // buf 'cur' collectively staged
        __builtin_amdgcn_sched_barrier(0);        // no ds_read hoisting above barrier

        half8 af[4], bf[4];
#pragma unroll
        for (int t = 0; t < 4; t++) {
            af[t] = *(const half8*)&Ac[(wm + t * 16 + mrow) * 32 + fc];
            bf[t] = *(const half8*)&Bc[(wn + t * 16 + mrow) * 32 + fc];
        }
#pragma unroll
        for (int mt = 0; mt < 4; mt++)
#pragma unroll
            for (int nt = 0; nt < 4; nt++)
                acc[mt][nt] = __builtin_amdgcn_mfma_f32_16x16x32_f16(af[mt], bf[nt], acc[mt][nt], 0, 0, 0);

        __builtin_amdgcn_sched_barrier(0);        // no ds_read sinking below release
        __builtin_amdgcn_s_barrier();             // release 'cur' for overwrite
    }

#pragma unroll
    for (int nt = 0; nt < 4; nt++) {
        int col = c0 + wn + nt * 16 + (l & 15);
        float bv = bias ? bias[col] : 0.f;
#pragma unroll
        for (int mt = 0; mt < 4; mt++) {
#pragma unroll
            for (int r = 0; r < 4; r++) {
                int row = r0 + wm + mt * 16 + (l >> 4) * 4 + r;
                if (row < M) {
                    if (OUT_F32) ((float*)Y)[(size_t)row * ldY + col] = acc[mt][nt][r] + bv;
                    else ((_Float16*)Y)[(size_t)row * ldY + col] = (_Float16)acc[mt][nt][r];
                }
            }
        }
    }
}

// ---------------- MFMA GEMM body, 128x64 tile (N-split for grid fill) --------------
// R10: proj's 594-block grid fills 2.32 blocks/CU -> wall = 3 blocks, 23% CUs idle.
// Split N: 99rb x 12cb = 1188 blocks (4.64/CU, ~93% fill). Same inner loop; B-panel
// is 64 cols (1 stage slot/wave), acc[4][2], 3 loads/iter -> vmcnt(3). Per-output-
// element K accumulation order unchanged -> bit-identical (R4 precedent).
// LDS = 2 x (128+64) x 32 halfs = 24 KB.
template <int OUT_F32>
__device__ __forceinline__ void gemm_body_n64(
    const _Float16* __restrict__ A, const _Float16* __restrict__ W,
    const float* __restrict__ bias, void* __restrict__ Y,
    int M, int Woff, int ldY, int r0, int c0,
    _Float16* As0, _Float16* Bs0, _Float16* As1, _Float16* Bs1)
{
    const int tid = threadIdx.x;
    const int w = tid >> 6, l = tid & 63;
    const int wm = (w >> 1) * 64, wn = (w & 1) * 32;   // 2x2 waves over 128x64
    const int cg = (l & 3) ^ ((l >> 3) & 3);           // swizzled global chunk

    const _Float16* sa[2];
    int soffA[2];
#pragma unroll
    for (int i = 0; i < 2; i++) {
        int rt = w * 32 + i * 16 + (l >> 2);
        int ra = min(r0 + rt, M - 1);
        sa[i] = A + (size_t)ra * CDIM + cg * 8;
        soffA[i] = (w * 32 + i * 16) * 32;
    }
    const _Float16* sb;
    {
        int rt = w * 16 + (l >> 2);
        sb = W + (size_t)(Woff + c0 + rt) * CDIM + cg * 8;
    }
    const int soffB = (w * 16) * 32;

    // prologue: stage tile 0 (2 A + 1 B loads/wave)
#pragma unroll
    for (int i = 0; i < 2; i++)
        __builtin_amdgcn_global_load_lds((GPTR*)sa[i], (LPTR*)(As0 + soffA[i]), 16, 0, 0);
    __builtin_amdgcn_global_load_lds((GPTR*)sb, (LPTR*)(Bs0 + soffB), 16, 0, 0);

    floatx4 acc[4][2] = {};
    const int fc = ((l >> 4) ^ ((l >> 1) & 3)) * 8;
    const int mrow = l & 15;
    const int lm = l & 15, lq = l >> 4;

#pragma unroll
    for (int it = 0; it < 24; it++) {
        const _Float16* Ac = (it & 1) ? As1 : As0;
        const _Float16* Bc = (it & 1) ? Bs1 : Bs0;
        _Float16* An = (it & 1) ? As0 : As1;
        _Float16* Bn = (it & 1) ? Bs0 : Bs1;

        if (it < 23) {
            int kb = (it + 1) * 32;
#pragma unroll
            for (int i = 0; i < 2; i++)
                __builtin_amdgcn_global_load_lds((GPTR*)(sa[i] + kb), (LPTR*)(An + soffA[i]), 16, 0, 0);
            __builtin_amdgcn_global_load_lds((GPTR*)(sb + kb), (LPTR*)(Bn + soffB), 16, 0, 0);
            __builtin_amdgcn_s_waitcnt(0x0073);   // vmcnt(3) lgkm(0): tile it's 3 loads done
        } else {
            __builtin_amdgcn_s_waitcnt(0x0070);   // vmcnt(0) lgkmcnt(0)
        }
        __builtin_amdgcn_s_barrier();             // buf 'cur' collectively staged
        __builtin_amdgcn_sched_barrier(0);        // no ds_read hoisting above barrier

        half8 af[4], bf[2];
#pragma unroll
        for (int t = 0; t < 4; t++)
            af[t] = *(const half8*)&Ac[(wm + t * 16 + mrow) * 32 + fc];
#pragma unroll
        for (int t = 0; t < 2; t++)
            bf[t] = *(const half8*)&Bc[(wn + t * 16 + mrow) * 32 + fc];
#pragma unroll
        for (int mt = 0; mt < 4; mt++)
#pragma unroll
            for (int nt = 0; nt < 2; nt++)
                acc[mt][nt] = __builtin_amdgcn_mfma_f32_16x16x32_f16(af[mt], bf[nt], acc[mt][nt], 0, 0, 0);

        __builtin_amdgcn_sched_barrier(0);        // no ds_read sinking below release
        __builtin_amdgcn_s_barrier();             // release 'cur' for overwrite
    }

#pragma unroll
    for (int nt = 0; nt < 2; nt++) {
        int col = c0 + wn + nt * 16 + lm;
        float bv = bias ? bias[col] : 0.f;
#pragma unroll
        for (int mt = 0; mt < 4; mt++) {
#pragma unroll
            for (int r = 0; r < 4; r++) {
                int row = r0 + wm + mt * 16 + lq * 4 + r;
                if (row < M) {
                    if (OUT_F32) ((float*)Y)[(size_t)row * ldY + col] = acc[mt][nt][r] + bv;
                    else ((_Float16*)Y)[(size_t)row * ldY + col] = (_Float16)acc[mt][nt][r];
                }
            }
        }
    }
}

// Q GEMM: 594 work ids (grid padded to 600 to keep the KV part's XCD phase);
// xcd_chunk puts batch b's token rows on XCD b. KV GEMM: 156 ids, same alignment.
// qkv fills 2.95/CU (98% of 3-block wall) -> keep 128x128 tiles (R4: split is null).
__global__ __launch_bounds__(256) void gemm_qkv(
    const _Float16* __restrict__ xh, const _Float16* __restrict__ qkvwh,
    _Float16* __restrict__ Qh, _Float16* __restrict__ KVh)
{
    __shared__ __align__(16) _Float16 As0[128 * 32];
    __shared__ __align__(16) _Float16 Bs0[128 * 32];
    __shared__ __align__(16) _Float16 As1[128 * 32];
    __shared__ __align__(16) _Float16 Bs1[128 * 32];
    int bx = blockIdx.x;
    if (bx < 600) {
        if (bx >= 594) return;                    // 6 pad blocks
        int wg = xcd_chunk(bx, 594);
        int rb = wg / 6, cb = wg - rb * 6;
        gemm_body<0>(xh, qkvwh, nullptr, Qh, TOKENS, 0, CDIM, 0,
                     rb * 128, cb * 128, As0, Bs0, As1, Bs1);
    } else {
        int b2 = bx - 600;
        int wg = xcd_chunk(b2, 156);
        int rb = wg / 12, cb = wg - rb * 12;
        gemm_body<0>(xh, qkvwh, nullptr, KVh, BATCH * MG, CDIM, 1536, 1,
                     rb * 128, cb * 128, As0, Bs0, As1, Bs1);
    }
}

// proj: 99rb x 12cb = 1188 blocks of 128x64 -> 4.64/CU, ~93% fill (was 77%).
// xcd_chunk keeps batch alignment (XCD k owns rb ~ 12.4k = batch k's AO rows).
__global__ __launch_bounds__(256) void gemm_proj(
    const _Float16* __restrict__ AOh, const _Float16* __restrict__ projwh,
    const float* __restrict__ bias, float* __restrict__ out)
{
    __shared__ __align__(16) _Float16 As0[128 * 32];
    __shared__ __align__(16) _Float16 Bs0[64 * 32];
    __shared__ __align__(16) _Float16 As1[128 * 32];
    __shared__ __align__(16) _Float16 Bs1[64 * 32];
    int wg = xcd_chunk(blockIdx.x, 1188);
    int rb = wg / 12, cb = wg - rb * 12;
    gemm_body_n64<1>(AOh, projwh, bias, out, TOKENS, 0, CDIM,
                     rb * 128, cb * 64, As0, Bs0, As1, Bs1);
}

// ---------------- fused masked attention, MFMA ----------------
// R10: q-chunks 320 -> 192 (grid 480 -> 864 = 3.375/CU) to cut the 2-round tail
// (480 blocks at 2/CU left 32 CUs half-loaded). b = id&7 keeps batch b on XCD b.
// block = (b,h) x 192 q-rows (3 row-tiles of 16 per wave). K/V staged ONCE.
// LDS = 80384 B -> 2 blocks/CU. setprio around MFMA clusters (T5-proven).
__global__ __launch_bounds__(256, 2) void attn_mfma(
    const _Float16* __restrict__ Qh, const _Float16* __restrict__ KVh,
    _Float16* __restrict__ AOh)
{
    __shared__ __align__(16) _Float16 Ks[204 * 64];  // [row][chunk^(row&7)]
    __shared__ __align__(16) _Float16 Vt[64 * 208];
    __shared__ __align__(16) _Float16 Ps[64 * 216];  // wave w owns rows [w*16, +16)

    const int tid = threadIdx.x;
    const int id = blockIdx.x;
    const int b = id & 7;                 // XCD = id%8 -> batch b on XCD b
    const int j = id >> 3;                // [0,108)
    const int h = j % NHEAD;
    const int qc0 = (j / NHEAD) * 192;    // 9 chunks x 192 = 1728 >= 1576

    for (int e = tid; e < MG * 8; e += 256) {
        int row = e >> 3, c8 = e & 7;
        half8 v = *(const half8*)&KVh[(size_t)(b * MG + row) * 1536 + h * 64 + c8 * 8];
        *(half8*)&Ks[row * 64 + ((c8 ^ (row & 7)) * 8)] = v;
    }
    {
        const int d0 = (tid >> 5) * 8, lmp = tid & 31;
#pragma unroll
        for (int mo = 0; mo < 7; mo++) {
            int mp = mo * 32 + lmp;
            if (mp >= 208) continue;
            half8 v = {};
            if (mp < MG) v = *(const half8*)&KVh[(size_t)(b * MG + mp) * 1536 + 768 + h * 64 + d0];
#pragma unroll
            for (int jj = 0; jj < 8; jj++) Vt[(d0 + jj) * 208 + mp] = v[jj];
        }
    }
    __syncthreads();

    const int w = tid >> 6, l = tid & 63;
    const int lm = l & 15, lq = l >> 4;

    int cf[13];
#pragma unroll
    for (int t = 0; t < 13; t++) {
        int col = t * 16 + lm;
        cf[t] = (col < 8) ? -1 : (col >= MG ? -2 : col_frame(col));
    }

    _Float16* Pw = &Ps[(w * 16) * 216];

    for (int t5 = 0; t5 < 3; t5++) {
        const int rb = qc0 + t5 * 64 + w * 16;
        if (rb >= NTOK) break;   // per-wave exit; no barriers below

        floatx4 acc[13] = {};
        const int qrowA = min(rb + lm, NTOK - 1);
        const _Float16* qbase = Qh + (size_t)(b * NTOK + qrowA) * CDIM + h * 64;
        __builtin_amdgcn_s_setprio(1);
#pragma unroll
        for (int ks = 0; ks < 64; ks += 32) {
            half8 aq = *(const half8*)(qbase + ks + lq * 8);
#pragma unroll
            for (int t = 0; t < 13; t++) {
                half8 bk = *(const half8*)&Ks[(t * 16 + lm) * 64 + (((ks >> 3) + lq) ^ (lm & 7)) * 8];
                acc[t] = __builtin_amdgcn_mfma_f32_16x16x32_f16(aq, bk, acc[t], 0, 0, 0);
            }
        }
        __builtin_amdgcn_s_setprio(0);

#pragma unroll
        for (int r = 0; r < 4; r++) {
            int qrow = min(rb + lq * 4 + r, NTOK - 1);
            int rf = qrow / NORI;
            float sv[13];
            float mx = -1e30f;
#pragma unroll
            for (int t = 0; t < 13; t++) {
                float s = acc[t][r] * 0.125f;
                s *= (cf[t] == -1 || cf[t] == rf) ? 1.f : 0.8f;
                if (cf[t] == -2) s = -1e30f;
                sv[t] = s;
                mx = fmaxf(mx, s);
            }
#pragma unroll
            for (int off = 1; off < 16; off <<= 1) mx = fmaxf(mx, __shfl_xor(mx, off, 64));
            float sum = 0.f;
#pragma unroll
            for (int t = 0; t < 13; t++) { sv[t] = __expf(sv[t] - mx); sum += sv[t]; }
#pragma unroll
            for (int off = 1; off < 16; off <<= 1) sum += __shfl_xor(sum, off, 64);
            float inv = 1.f / sum;
#pragma unroll
            for (int t = 0; t < 13; t++) acc[t][r] = sv[t] * inv;
        }

#pragma unroll
        for (int t = 0; t < 13; t++)
#pragma unroll
            for (int r = 0; r < 4; r++)
                Pw[(lq * 4 + r) * 216 + t * 16 + lm] = (_Float16)acc[t][r];

        floatx4 oacc[4] = {};
        const _Float16* prow = &Pw[lm * 216];
        __builtin_amdgcn_s_setprio(1);
#pragma unroll
        for (int ks = 0; ks < 192; ks += 32) {
            half8 ap = *(const half8*)(prow + ks + lq * 8);
#pragma unroll
            for (int t = 0; t < 4; t++) {
                half8 bv = *(const half8*)&Vt[(t * 16 + lm) * 208 + ks + lq * 8];
                oacc[t] = __builtin_amdgcn_mfma_f32_16x16x32_f16(ap, bv, oacc[t], 0, 0, 0);
            }
        }
        {
            typedef _Float16 half4v __attribute__((ext_vector_type(4)));
            half4v ap4 = *(const half4v*)(prow + 192 + lq * 4);
#pragma unroll
            for (int t = 0; t < 4; t++) {
                half4v bv4 = *(const half4v*)&Vt[(t * 16 + lm) * 208 + 192 + lq * 4];
                oacc[t] = __builtin_amdgcn_mfma_f32_16x16x16f16(ap4, bv4, oacc[t], 0, 0, 0);
            }
        }
        __builtin_amdgcn_s_setprio(0);

#pragma unroll
        for (int t = 0; t < 4; t++)
#pragma unroll
            for (int r = 0; r < 4; r++) {
                int qrow = rb + lq * 4 + r;
                if (qrow < NTOK)
                    AOh[(size_t)(b * NTOK + qrow) * CDIM + h * 64 + t * 16 + lm] = (_Float16)oacc[t][r];
            }
    }
}

extern "C" void kernel_launch(void* const* d_in, const int* in_sizes, int n_in,
                              void* d_out, int out_size, void* d_ws, size_t ws_size,
                              hipStream_t stream) {
    const float* x      = (const float*)d_in[0];
    const float* qkv_w  = (const float*)d_in[1];
    const float* proj_w = (const float*)d_in[2];
    const float* proj_b = (const float*)d_in[3];
    float* out = (float*)d_out;

    _Float16* xh     = (_Float16*)d_ws;
    _Float16* qkvwh  = xh + (size_t)TOKENS * CDIM;
    _Float16* projwh = qkvwh + (size_t)3 * CDIM * CDIM;
    _Float16* Qh     = projwh + (size_t)CDIM * CDIM;
    _Float16* KVh    = Qh + (size_t)TOKENS * CDIM;
    _Float16* AOh    = KVh + (size_t)(BATCH * MG) * 1536;

    dim3 blk(256);
    const int ncast = (TOKENS * CDIM + 3 * CDIM * CDIM + CDIM * CDIM) / 8;
    cast_all<<<dim3((ncast + 255) / 256), blk, 0, stream>>>(x, qkv_w, proj_w, xh);

    gemm_qkv<<<dim3(600 + 156), blk, 0, stream>>>(xh, qkvwh, Qh, KVh);

    attn_mfma<<<dim3(864), blk, 0, stream>>>(Qh, KVh, AOh);

    gemm_proj<<<dim3(1188), blk, 0, stream>>>(AOh, projwh, proj_b, out);
}

// Round 11
// 180.922 us; speedup vs baseline: 1.1909x; 1.0278x over previous
//
#include <hip/hip_runtime.h>
#include <stdint.h>

#define NORI   197
#define FRAMES 8
#define NTOK   1576
#define BATCH  8
#define NHEAD  12
#define CDIM   768
#define MG     204
#define TOKENS 12608

typedef _Float16 half8 __attribute__((ext_vector_type(8)));
typedef float floatx4 __attribute__((ext_vector_type(4)));

typedef const __attribute__((address_space(1))) void GPTR;
typedef __attribute__((address_space(3))) void LPTR;

__device__ __forceinline__ int gather_idx(int m) {
    if (m < 8) return m * NORI;
    int u = m - 8;
    int f, t;
    if (u < 100) { f = u / 25; t = u - f * 25; }
    else         { f = 4 + (u - 100) / 24; t = (u - 100) - (f - 4) * 24; }
    return f * NORI + 1 + f + 8 * t;
}
__device__ __forceinline__ int col_frame(int m) {  // m in [8,204)
    int u = m - 8;
    return (u < 100) ? (u / 25) : (4 + (u - 100) / 24);
}

// Bijective XCD-chunked remap (m204 form): block bid runs on XCD bid%8; give XCD k
// the k-th contiguous chunk of work ids so producer/consumer chunks coincide.
__device__ __forceinline__ int xcd_chunk(int bid, int nwg) {
    int xcd = bid & 7, j = bid >> 3;
    int q = nwg >> 3, r = nwg & 7;
    int base = (xcd < r) ? xcd * (q + 1) : r * (q + 1) + (xcd - r) * q;
    return base + j;
}

// ---------------- fused fp32 -> fp16 cast of x, qkv_w, proj_w ----------------
// R7-proven: x-region blocks XCD-chunk remapped so batch b's xh is written on the
// XCD whose gemm_qkv blocks read it. Weight blocks unmapped (read by all).
__global__ __launch_bounds__(256) void cast_all(
    const float* __restrict__ x, const float* __restrict__ qkvw,
    const float* __restrict__ projw, _Float16* __restrict__ out)
{
    const int n1 = TOKENS * CDIM / 8, n2 = 3 * CDIM * CDIM / 8, n3 = CDIM * CDIM / 8;
    const int nxb = n1 / 256;                       // 4728, divisible by 8
    int bx = blockIdx.x;
    int i;
    if (bx < nxb) i = xcd_chunk(bx, nxb) * 256 + threadIdx.x;
    else          i = bx * 256 + threadIdx.x;
    if (i >= n1 + n2 + n3) return;
    const float* src; int off;
    if (i < n1)           { src = x;     off = i; }
    else if (i < n1 + n2) { src = qkvw;  off = i - n1; }
    else                  { src = projw; off = i - n1 - n2; }
    float4 a = ((const float4*)src)[2 * off];
    float4 b = ((const float4*)src)[2 * off + 1];
    half8 o = { (_Float16)a.x, (_Float16)a.y, (_Float16)a.z, (_Float16)a.w,
                (_Float16)b.x, (_Float16)b.y, (_Float16)b.z, (_Float16)b.w };
    ((half8*)out)[i] = o;
}

// ---------------- MFMA GEMM body, 128x128, BK=32, double-buffered (R0 exact) -------
// The 2-phase structure's per-MFLOP cost (~1350 cy/MFLOP) is invariant across tile
// shape (R4), residency (R4), prefetch depth (R5), staging style (R6/R8), barrier
// count (R9), and grid fill (R10). This is the best-measured form; only the XCD
// producer->consumer locality lever (R7) moved total time.
template <int OUT_F32>
__device__ __forceinline__ void gemm_body(
    const _Float16* __restrict__ A, const _Float16* __restrict__ W,
    const float* __restrict__ bias, void* __restrict__ Y,
    int M, int Woff, int ldY, int gather, int r0, int c0,
    _Float16* As0, _Float16* Bs0, _Float16* As1, _Float16* Bs1)
{
    const int tid = threadIdx.x;
    const int w = tid >> 6, l = tid & 63;
    const int wm = (w >> 1) * 64, wn = (w & 1) * 64;

    const _Float16* sa[2];
    const _Float16* sb[2];
    int soff[2];
#pragma unroll
    for (int i = 0; i < 2; i++) {
        int rt = w * 32 + i * 16 + (l >> 2);
        int cg = (l & 3) ^ ((l >> 3) & 3);       // swizzled global chunk
        int ra = min(r0 + rt, M - 1);
        if (gather) { int b = ra / MG; int m = ra - b * MG; ra = b * NTOK + gather_idx(m); }
        sa[i] = A + (size_t)ra * CDIM + cg * 8;
        sb[i] = W + (size_t)(Woff + c0 + rt) * CDIM + cg * 8;
        soff[i] = (w * 32 + i * 16) * 32;
    }

    // prologue: stage tile 0 into buf0
#pragma unroll
    for (int i = 0; i < 2; i++) {
        __builtin_amdgcn_global_load_lds((GPTR*)sa[i], (LPTR*)(As0 + soff[i]), 16, 0, 0);
        __builtin_amdgcn_global_load_lds((GPTR*)sb[i], (LPTR*)(Bs0 + soff[i]), 16, 0, 0);
    }

    floatx4 acc[4][4] = {};
    const int fc = ((l >> 4) ^ ((l >> 1) & 3)) * 8;
    const int mrow = l & 15;

#pragma unroll
    for (int it = 0; it < 24; it++) {
        const _Float16* Ac = (it & 1) ? As1 : As0;
        const _Float16* Bc = (it & 1) ? Bs1 : Bs0;
        _Float16* An = (it & 1) ? As0 : As1;
        _Float16* Bn = (it & 1) ? Bs0 : Bs1;

        if (it < 23) {
            int kb = (it + 1) * 32;
#pragma unroll
            for (int i = 0; i < 2; i++) {
                __builtin_amdgcn_global_load_lds((GPTR*)(sa[i] + kb), (LPTR*)(An + soff[i]), 16, 0, 0);
                __builtin_amdgcn_global_load_lds((GPTR*)(sb[i] + kb), (LPTR*)(Bn + soff[i]), 16, 0, 0);
            }
            __builtin_amdgcn_s_waitcnt(0x0074);   // vmcnt(4) expcnt(7) lgkmcnt(0)
        } else {
            __builtin_amdgcn_s_waitcnt(0x0070);   // vmcnt(0) lgkmcnt(0)
        }
        __builtin_amdgcn_s_barrier();             // buf 'cur' collectively staged
        __builtin_amdgcn_sched_barrier(0);        // no ds_read hoisting above barrier

        half8 af[4], bf[4];
#pragma unroll
        for (int t = 0; t < 4; t++) {
            af[t] = *(const half8*)&Ac[(wm + t * 16 + mrow) * 32 + fc];
            bf[t] = *(const half8*)&Bc[(wn + t * 16 + mrow) * 32 + fc];
        }
#pragma unroll
        for (int mt = 0; mt < 4; mt++)
#pragma unroll
            for (int nt = 0; nt < 4; nt++)
                acc[mt][nt] = __builtin_amdgcn_mfma_f32_16x16x32_f16(af[mt], bf[nt], acc[mt][nt], 0, 0, 0);

        __builtin_amdgcn_sched_barrier(0);        // no ds_read sinking below release
        __builtin_amdgcn_s_barrier();             // release 'cur' for overwrite
    }

#pragma unroll
    for (int nt = 0; nt < 4; nt++) {
        int col = c0 + wn + nt * 16 + (l & 15);
        float bv = bias ? bias[col] : 0.f;
#pragma unroll
        for (int mt = 0; mt < 4; mt++) {
#pragma unroll
            for (int r = 0; r < 4; r++) {
                int row = r0 + wm + mt * 16 + (l >> 4) * 4 + r;
                if (row < M) {
                    if (OUT_F32) ((float*)Y)[(size_t)row * ldY + col] = acc[mt][nt][r] + bv;
                    else ((_Float16*)Y)[(size_t)row * ldY + col] = (_Float16)acc[mt][nt][r];
                }
            }
        }
    }
}

// Q GEMM: 594 work ids (grid padded to 600 to keep the KV part's XCD phase);
// xcd_chunk puts batch b's token rows on XCD b. KV GEMM: 156 ids, same alignment.
__global__ __launch_bounds__(256) void gemm_qkv(
    const _Float16* __restrict__ xh, const _Float16* __restrict__ qkvwh,
    _Float16* __restrict__ Qh, _Float16* __restrict__ KVh)
{
    __shared__ __align__(16) _Float16 As0[128 * 32];
    __shared__ __align__(16) _Float16 Bs0[128 * 32];
    __shared__ __align__(16) _Float16 As1[128 * 32];
    __shared__ __align__(16) _Float16 Bs1[128 * 32];
    int bx = blockIdx.x;
    if (bx < 600) {
        if (bx >= 594) return;                    // 6 pad blocks
        int wg = xcd_chunk(bx, 594);
        int rb = wg / 6, cb = wg - rb * 6;
        gemm_body<0>(xh, qkvwh, nullptr, Qh, TOKENS, 0, CDIM, 0,
                     rb * 128, cb * 128, As0, Bs0, As1, Bs1);
    } else {
        int b2 = bx - 600;
        int wg = xcd_chunk(b2, 156);
        int rb = wg / 12, cb = wg - rb * 12;
        gemm_body<0>(xh, qkvwh, nullptr, KVh, BATCH * MG, CDIM, 1536, 1,
                     rb * 128, cb * 128, As0, Bs0, As1, Bs1);
    }
}

__global__ __launch_bounds__(256) void gemm_proj(
    const _Float16* __restrict__ AOh, const _Float16* __restrict__ projwh,
    const float* __restrict__ bias, float* __restrict__ out)
{
    __shared__ __align__(16) _Float16 As0[128 * 32];
    __shared__ __align__(16) _Float16 Bs0[128 * 32];
    __shared__ __align__(16) _Float16 As1[128 * 32];
    __shared__ __align__(16) _Float16 Bs1[128 * 32];
    int wg = xcd_chunk(blockIdx.x, 594);
    int rb = wg / 6, cb = wg - rb * 6;
    gemm_body<1>(AOh, projwh, bias, out, TOKENS, 0, CDIM, 0,
                 rb * 128, cb * 128, As0, Bs0, As1, Bs1);
}

// ---------------- fused masked attention, MFMA (R7 exact) ----------------
// 1-D grid 480, batch b on XCD b (b = id%8): Q/KV reads and AO write stay in the
// XCD-local L2. block = (b,h) x 320 q-rows. K/V staged ONCE. 80384 B LDS -> 2/CU.
__global__ __launch_bounds__(256, 2) void attn_mfma(
    const _Float16* __restrict__ Qh, const _Float16* __restrict__ KVh,
    _Float16* __restrict__ AOh)
{
    __shared__ __align__(16) _Float16 Ks[204 * 64];  // [row][chunk^(row&7)]
    __shared__ __align__(16) _Float16 Vt[64 * 208];
    __shared__ __align__(16) _Float16 Ps[64 * 216];  // wave w owns rows [w*16, +16)

    const int tid = threadIdx.x;
    const int id = blockIdx.x;
    const int b = id & 7;                 // XCD = id%8 -> batch b on XCD b
    const int j = id >> 3;                // [0,60)
    const int h = j % NHEAD;
    const int qc0 = (j / NHEAD) * 320;

    for (int e = tid; e < MG * 8; e += 256) {
        int row = e >> 3, c8 = e & 7;
        half8 v = *(const half8*)&KVh[(size_t)(b * MG + row) * 1536 + h * 64 + c8 * 8];
        *(half8*)&Ks[row * 64 + ((c8 ^ (row & 7)) * 8)] = v;
    }
    {
        const int d0 = (tid >> 5) * 8, lmp = tid & 31;
#pragma unroll
        for (int mo = 0; mo < 7; mo++) {
            int mp = mo * 32 + lmp;
            if (mp >= 208) continue;
            half8 v = {};
            if (mp < MG) v = *(const half8*)&KVh[(size_t)(b * MG + mp) * 1536 + 768 + h * 64 + d0];
#pragma unroll
            for (int jj = 0; jj < 8; jj++) Vt[(d0 + jj) * 208 + mp] = v[jj];
        }
    }
    __syncthreads();

    const int w = tid >> 6, l = tid & 63;
    const int lm = l & 15, lq = l >> 4;

    int cf[13];
#pragma unroll
    for (int t = 0; t < 13; t++) {
        int col = t * 16 + lm;
        cf[t] = (col < 8) ? -1 : (col >= MG ? -2 : col_frame(col));
    }

    _Float16* Pw = &Ps[(w * 16) * 216];

    for (int t5 = 0; t5 < 5; t5++) {
        const int rb = qc0 + t5 * 64 + w * 16;
        if (rb >= NTOK) break;   // per-wave exit; no barriers below

        floatx4 acc[13] = {};
        const int qrowA = min(rb + lm, NTOK - 1);
        const _Float16* qbase = Qh + (size_t)(b * NTOK + qrowA) * CDIM + h * 64;
        __builtin_amdgcn_s_setprio(1);
#pragma unroll
        for (int ks = 0; ks < 64; ks += 32) {
            half8 aq = *(const half8*)(qbase + ks + lq * 8);
#pragma unroll
            for (int t = 0; t < 13; t++) {
                half8 bk = *(const half8*)&Ks[(t * 16 + lm) * 64 + (((ks >> 3) + lq) ^ (lm & 7)) * 8];
                acc[t] = __builtin_amdgcn_mfma_f32_16x16x32_f16(aq, bk, acc[t], 0, 0, 0);
            }
        }
        __builtin_amdgcn_s_setprio(0);

#pragma unroll
        for (int r = 0; r < 4; r++) {
            int qrow = min(rb + lq * 4 + r, NTOK - 1);
            int rf = qrow / NORI;
            float sv[13];
            float mx = -1e30f;
#pragma unroll
            for (int t = 0; t < 13; t++) {
                float s = acc[t][r] * 0.125f;
                s *= (cf[t] == -1 || cf[t] == rf) ? 1.f : 0.8f;
                if (cf[t] == -2) s = -1e30f;
                sv[t] = s;
                mx = fmaxf(mx, s);
            }
#pragma unroll
            for (int off = 1; off < 16; off <<= 1) mx = fmaxf(mx, __shfl_xor(mx, off, 64));
            float sum = 0.f;
#pragma unroll
            for (int t = 0; t < 13; t++) { sv[t] = __expf(sv[t] - mx); sum += sv[t]; }
#pragma unroll
            for (int off = 1; off < 16; off <<= 1) sum += __shfl_xor(sum, off, 64);
            float inv = 1.f / sum;
#pragma unroll
            for (int t = 0; t < 13; t++) acc[t][r] = sv[t] * inv;
        }

#pragma unroll
        for (int t = 0; t < 13; t++)
#pragma unroll
            for (int r = 0; r < 4; r++)
                Pw[(lq * 4 + r) * 216 + t * 16 + lm] = (_Float16)acc[t][r];

        floatx4 oacc[4] = {};
        const _Float16* prow = &Pw[lm * 216];
        __builtin_amdgcn_s_setprio(1);
#pragma unroll
        for (int ks = 0; ks < 192; ks += 32) {
            half8 ap = *(const half8*)(prow + ks + lq * 8);
#pragma unroll
            for (int t = 0; t < 4; t++) {
                half8 bv = *(const half8*)&Vt[(t * 16 + lm) * 208 + ks + lq * 8];
                oacc[t] = __builtin_amdgcn_mfma_f32_16x16x32_f16(ap, bv, oacc[t], 0, 0, 0);
            }
        }
        {
            typedef _Float16 half4v __attribute__((ext_vector_type(4)));
            half4v ap4 = *(const half4v*)(prow + 192 + lq * 4);
#pragma unroll
            for (int t = 0; t < 4; t++) {
                half4v bv4 = *(const half4v*)&Vt[(t * 16 + lm) * 208 + 192 + lq * 4];
                oacc[t] = __builtin_amdgcn_mfma_f32_16x16x16f16(ap4, bv4, oacc[t], 0, 0, 0);
            }
        }
        __builtin_amdgcn_s_setprio(0);

#pragma unroll
        for (int t = 0; t < 4; t++)
#pragma unroll
            for (int r = 0; r < 4; r++) {
                int qrow = rb + lq * 4 + r;
                if (qrow < NTOK)
                    AOh[(size_t)(b * NTOK + qrow) * CDIM + h * 64 + t * 16 + lm] = (_Float16)oacc[t][r];
            }
    }
}

extern "C" void kernel_launch(void* const* d_in, const int* in_sizes, int n_in,
                              void* d_out, int out_size, void* d_ws, size_t ws_size,
                              hipStream_t stream) {
    const float* x      = (const float*)d_in[0];
    const float* qkv_w  = (const float*)d_in[1];
    const float* proj_w = (const float*)d_in[2];
    const float* proj_b = (const float*)d_in[3];
    float* out = (float*)d_out;

    _Float16* xh     = (_Float16*)d_ws;
    _Float16* qkvwh  = xh + (size_t)TOKENS * CDIM;
    _Float16* projwh = qkvwh + (size_t)3 * CDIM * CDIM;
    _Float16* Qh     = projwh + (size_t)CDIM * CDIM;
    _Float16* KVh    = Qh + (size_t)TOKENS * CDIM;
    _Float16* AOh    = KVh + (size_t)(BATCH * MG) * 1536;

    dim3 blk(256);
    const int ncast = (TOKENS * CDIM + 3 * CDIM * CDIM + CDIM * CDIM) / 8;
    cast_all<<<dim3((ncast + 255) / 256), blk, 0, stream>>>(x, qkv_w, proj_w, xh);

    gemm_qkv<<<dim3(600 + 156), blk, 0, stream>>>(xh, qkvwh, Qh, KVh);

    attn_mfma<<<dim3(480), blk, 0, stream>>>(Qh, KVh, AOh);

    gemm_proj<<<dim3(594), blk, 0, stream>>>(AOh, projwh, proj_b, out);
}